// Round 6
// baseline (1251.495 us; speedup 1.0000x reference)
//
#include <hip/hip_runtime.h>
#include <hip/hip_bf16.h>

// GNN classifier: 2x GCNConv + global_mean_pool + 2-layer MLP.
// R5: gather restructured for minimum dependent round-trips:
//  - one wave VMEM covers 8 edges (lane L: edge L>>3, 16B feature block L&7)
//  - edge-index prefetch overlaps next group's indices with current row load
//  - cross-lane shfl_xor reduction combines the 8 edge-groups at the end

#define NGRAPHS 256

__device__ __forceinline__ float bflo(unsigned u) { return __uint_as_float(u << 16); }
__device__ __forceinline__ float bfhi(unsigned u) { return __uint_as_float(u & 0xffff0000u); }
__device__ __forceinline__ unsigned short bfpack1(float v) {
  unsigned ua = __float_as_uint(v);
  ua += 0x7fffu + ((ua >> 16) & 1u);  // RNE
  return (unsigned short)(ua >> 16);
}
__device__ __forceinline__ unsigned bfpack2(float a, float b) {
  unsigned ua = __float_as_uint(a), ub = __float_as_uint(b);
  ua += 0x7fffu + ((ua >> 16) & 1u);
  ub += 0x7fffu + ((ub >> 16) & 1u);
  return (ua >> 16) | (ub & 0xffff0000u);
}

// ---------------- histogram of dst ----------------
__global__ __launch_bounds__(256) void hist_kernel(const int* __restrict__ dst,
                                                   int* __restrict__ deg, int E) {
  int stride = gridDim.x * 256;
  for (int e = blockIdx.x * 256 + threadIdx.x; e < E; e += stride)
    atomicAdd(&deg[dst[e]], 1);
}

// ---------------- scan stage 1 ----------------
__global__ __launch_bounds__(256) void scan1_kernel(const int* __restrict__ deg,
                                                    int* __restrict__ bsum, int N) {
  __shared__ int red[4];
  int t = threadIdx.x;
  int base = blockIdx.x * 1024;
  int s = 0;
  for (int i = t; i < 1024; i += 256) {
    int idx = base + i;
    if (idx < N) s += deg[idx];
  }
#pragma unroll
  for (int o = 32; o > 0; o >>= 1) s += __shfl_down(s, o);
  if ((t & 63) == 0) red[t >> 6] = s;
  __syncthreads();
  if (t == 0) bsum[blockIdx.x] = red[0] + red[1] + red[2] + red[3];
}

// ---------------- scan stage 2 ----------------
__global__ __launch_bounds__(64) void scan2_kernel(int* __restrict__ bsum, int nb) {
  int lane = threadIdx.x;
  int v0 = lane < nb ? bsum[lane] : 0;
  int v1 = (64 + lane) < nb ? bsum[64 + lane] : 0;
  int x0 = v0, x1 = v1;
#pragma unroll
  for (int o = 1; o < 64; o <<= 1) {
    int y = __shfl_up(x0, o);
    if (lane >= o) x0 += y;
  }
#pragma unroll
  for (int o = 1; o < 64; o <<= 1) {
    int y = __shfl_up(x1, o);
    if (lane >= o) x1 += y;
  }
  int tot0 = __shfl(x0, 63);
  if (lane < nb) bsum[lane] = x0 - v0;
  if ((64 + lane) < nb) bsum[64 + lane] = tot0 + x1 - v1;
}

// ---------------- scan stage 3: offsets + dis ----------------
__global__ __launch_bounds__(256) void scan3_kernel(const int* __restrict__ deg,
                                                    const int* __restrict__ bsum,
                                                    int* __restrict__ offs,
                                                    float* __restrict__ dis, int N) {
  __shared__ int wtot[4];
  int t = threadIdx.x, lane = t & 63, w = t >> 6;
  int base = blockIdx.x * 1024 + t * 4;
  int d0 = (base + 0) < N ? deg[base + 0] : 0;
  int d1 = (base + 1) < N ? deg[base + 1] : 0;
  int d2 = (base + 2) < N ? deg[base + 2] : 0;
  int d3 = (base + 3) < N ? deg[base + 3] : 0;
  int ts = d0 + d1 + d2 + d3;
  int x = ts;
#pragma unroll
  for (int o = 1; o < 64; o <<= 1) {
    int y = __shfl_up(x, o);
    if (lane >= o) x += y;
  }
  if (lane == 63) wtot[w] = x;
  __syncthreads();
  int woff = 0;
  for (int i = 0; i < w; ++i) woff += wtot[i];
  int o0 = bsum[blockIdx.x] + woff + (x - ts);
  int o1 = o0 + d0, o2 = o1 + d1, o3 = o2 + d2;
  if (base + 0 < N) { offs[base + 0] = o0; dis[base + 0] = rsqrtf((float)(d0 + 1)); }
  if (base + 1 < N) { offs[base + 1] = o1; dis[base + 1] = rsqrtf((float)(d1 + 1)); }
  if (base + 2 < N) { offs[base + 2] = o2; dis[base + 2] = rsqrtf((float)(d2 + 1)); }
  if (base + 3 < N) { offs[base + 3] = o3; dis[base + 3] = rsqrtf((float)(d3 + 1)); }
  if (base + 0 == N - 1) offs[N] = o0 + d0;
  if (base + 1 == N - 1) offs[N] = o1 + d1;
  if (base + 2 == N - 1) offs[N] = o2 + d2;
  if (base + 3 == N - 1) offs[N] = o3 + d3;
}

// ---------------- fill: edata[pos] = src, grouped by dst ----------------
__global__ __launch_bounds__(256) void fill_kernel(const int* __restrict__ src,
                                                   const int* __restrict__ dst,
                                                   const int* __restrict__ offs,
                                                   int* __restrict__ cur,
                                                   int* __restrict__ edata, int E) {
  int stride = gridDim.x * 256;
  for (int e = blockIdx.x * 256 + threadIdx.x; e < E; e += stride) {
    int d = dst[e];
    int pos = offs[d] + atomicAdd(&cur[d], 1);
    edata[pos] = src[e];
  }
}

// ---------------- gemm1: Y[n,64] = bf16( dis[n] * (X[n,128] @ W) ) ----------------
__global__ __launch_bounds__(256) void gemm1_kernel(const float* __restrict__ X,
                                                    const float* __restrict__ W,
                                                    const float* __restrict__ dis,
                                                    unsigned short* __restrict__ Y,
                                                    int nrows) {
  __shared__ float ws[128][64];
  __shared__ float xs[16][128];
  int t = threadIdx.x;

  const float4* W4 = (const float4*)W;
  float4* ws4 = (float4*)(&ws[0][0]);
  for (int i = t; i < 128 * 64 / 4; i += 256) ws4[i] = W4[i];

  int row0 = blockIdx.x * 16;
  int nr = min(16, nrows - row0);
  const float4* X4 = (const float4*)(X + (size_t)row0 * 128);
  float4* xs4 = (float4*)(&xs[0][0]);
  for (int i = t; i < nr * 128 / 4; i += 256) xs4[i] = X4[i];
  __syncthreads();

  int wave = t >> 6, lane = t & 63;
  for (int r = wave; r < nr; r += 4) {
    float acc = 0.f;
#pragma unroll
    for (int k = 0; k < 128; k += 4) {
      acc += xs[r][k + 0] * ws[k + 0][lane];
      acc += xs[r][k + 1] * ws[k + 1][lane];
      acc += xs[r][k + 2] * ws[k + 2][lane];
      acc += xs[r][k + 3] * ws[k + 3][lane];
    }
    Y[(size_t)(row0 + r) * 64 + lane] = bfpack1(acc * dis[row0 + r]);
  }
}

// ---------------- gemm2: Y[n,64] = bf16( dis[n] * (Xbf16[n,64] @ W) ) ----------------
__global__ __launch_bounds__(256) void gemm2_kernel(const unsigned* __restrict__ X32,
                                                    const float* __restrict__ W,
                                                    const float* __restrict__ dis,
                                                    unsigned short* __restrict__ Y,
                                                    int nrows) {
  __shared__ float ws[64][64];
  __shared__ unsigned xs[16][32];
  int t = threadIdx.x;

  const float4* W4 = (const float4*)W;
  float4* ws4 = (float4*)(&ws[0][0]);
  for (int i = t; i < 64 * 64 / 4; i += 256) ws4[i] = W4[i];

  int row0 = blockIdx.x * 16;
  int nr = min(16, nrows - row0);
  const uint4* X4 = (const uint4*)(X32 + (size_t)row0 * 32);
  uint4* xs4 = (uint4*)(&xs[0][0]);
  for (int i = t; i < nr * 32 / 4; i += 256) xs4[i] = X4[i];
  __syncthreads();

  int wave = t >> 6, lane = t & 63;
  for (int r = wave; r < nr; r += 4) {
    float acc = 0.f;
#pragma unroll
    for (int k2 = 0; k2 < 32; ++k2) {
      unsigned u = xs[r][k2];
      acc += bflo(u) * ws[2 * k2 + 0][lane];
      acc += bfhi(u) * ws[2 * k2 + 1][lane];
    }
    Y[(size_t)(row0 + r) * 64 + lane] = bfpack1(acc * dis[row0 + r]);
  }
}

// ---------------- gather helpers ----------------
__device__ __forceinline__ int select8(const int4& a, const int4& b, int sel) {
  int4 c;
  c.x = (sel & 4) ? b.x : a.x;
  c.y = (sel & 4) ? b.y : a.y;
  c.z = (sel & 4) ? b.z : a.z;
  c.w = (sel & 4) ? b.w : a.w;
  int lo = (sel & 1) ? c.y : c.x;
  int hi = (sel & 1) ? c.w : c.z;
  return (sel & 2) ? hi : lo;
}

__device__ __forceinline__ void accum8(float* acc, uint4 u) {
  acc[0] += bflo(u.x); acc[1] += bfhi(u.x);
  acc[2] += bflo(u.y); acc[3] += bfhi(u.y);
  acc[4] += bflo(u.z); acc[5] += bfhi(u.z);
  acc[6] += bflo(u.w); acc[7] += bfhi(u.w);
}

// ---------------- gather conv: one wave per dst node, 8 rows per VMEM ----
// lane L: edge sel=L>>3 within group of 8, feature block fb=L&7 (16B of row).
// out = dis[d]*(sum_e xw'[src_e] + xw'[d]) + bias
template <bool POOL>
__global__ __launch_bounds__(256) void gather_kernel(const int* __restrict__ edata,
                                                     const int* __restrict__ offs,
                                                     const float* __restrict__ dis,
                                                     const uint4* __restrict__ xw4,
                                                     const float* __restrict__ bias,
                                                     const int* __restrict__ batch,
                                                     uint4* __restrict__ out4,
                                                     float* __restrict__ psum,
                                                     float* __restrict__ pcnt, int N) {
  int lane = threadIdx.x & 63;
  int sel = lane >> 3;  // edge slot in group of 8
  int fb = lane & 7;    // 16B feature block within the 128B row
  int node = blockIdx.x * 4 + (threadIdx.x >> 6);
  if (node >= N) return;
  int beg = offs[node], end = offs[node + 1];
  float acc[8] = {0.f, 0.f, 0.f, 0.f, 0.f, 0.f, 0.f, 0.f};

  int j = beg;
  // prologue singles until 16B-aligned edata index (only sel==0 accumulates)
  for (; j < end && (j & 3); ++j) {
    uint4 u = xw4[(size_t)edata[j] * 8 + fb];
    if (sel == 0) accum8(acc, u);
  }
  int nfull = (end - j) >> 3;
  if (nfull > 0) {
    const int4* ep = (const int4*)(edata + j);
    int4 a = ep[0], b = ep[1];
    int g = 0;
    for (;;) {
      int idx = select8(a, b, sel);
      uint4 u = xw4[(size_t)idx * 8 + fb];  // 1 VMEM: 8 rows for 8 edges
      ++g;
      if (g >= nfull) { accum8(acc, u); break; }
      a = ep[2 * g];      // prefetch next group's indices while u is in flight
      b = ep[2 * g + 1];
      accum8(acc, u);
    }
    j += nfull * 8;
  }
  // tail singles
  for (; j < end; ++j) {
    uint4 u = xw4[(size_t)edata[j] * 8 + fb];
    if (sel == 0) accum8(acc, u);
  }

  // reduce the 8 edge-slots (lanes with same fb) -> every lane holds full sum
#pragma unroll
  for (int m = 8; m <= 32; m <<= 1) {
#pragma unroll
    for (int k = 0; k < 8; ++k) acc[k] += __shfl_xor(acc[k], m);
  }

  // self-loop once (all lanes identical per fb)
  accum8(acc, xw4[(size_t)node * 8 + fb]);

  float d = dis[node];
  float4 b0 = ((const float4*)bias)[fb * 2];
  float4 b1 = ((const float4*)bias)[fb * 2 + 1];
  float r0 = fmaf(d, acc[0], b0.x), r1 = fmaf(d, acc[1], b0.y);
  float r2 = fmaf(d, acc[2], b0.z), r3 = fmaf(d, acc[3], b0.w);
  float r4 = fmaf(d, acc[4], b1.x), r5 = fmaf(d, acc[5], b1.y);
  float r6 = fmaf(d, acc[6], b1.z), r7 = fmaf(d, acc[7], b1.w);

  if (POOL) {
    if (sel == 0) {
      int g = batch[node];
      float* p = &psum[g * 64 + fb * 8];
      atomicAdd(p + 0, r0); atomicAdd(p + 1, r1);
      atomicAdd(p + 2, r2); atomicAdd(p + 3, r3);
      atomicAdd(p + 4, r4); atomicAdd(p + 5, r5);
      atomicAdd(p + 6, r6); atomicAdd(p + 7, r7);
      if (fb == 0) atomicAdd(&pcnt[g], 1.0f);
    }
  } else {
    if (sel == 0) {
      uint4 o;
      o.x = bfpack2(fmaxf(r0, 0.f), fmaxf(r1, 0.f));
      o.y = bfpack2(fmaxf(r2, 0.f), fmaxf(r3, 0.f));
      o.z = bfpack2(fmaxf(r4, 0.f), fmaxf(r5, 0.f));
      o.w = bfpack2(fmaxf(r6, 0.f), fmaxf(r7, 0.f));
      out4[(size_t)node * 8 + fb] = o;
    }
  }
}

// ---------------- per-graph MLP ----------------
__global__ __launch_bounds__(64) void mlp_kernel(const float* __restrict__ psum,
                                                 const float* __restrict__ pcnt,
                                                 const float* __restrict__ Wf1,
                                                 const float* __restrict__ bf1,
                                                 const float* __restrict__ Wf2,
                                                 const float* __restrict__ bf2,
                                                 float* __restrict__ out) {
  int g = blockIdx.x;
  int lane = threadIdx.x;
  __shared__ float p[64];
  __shared__ float hh[32];
  float cnt = fmaxf(pcnt[g], 1.f);
  p[lane] = psum[g * 64 + lane] / cnt;
  __syncthreads();
  if (lane < 32) {
    float a = bf1[lane];
#pragma unroll
    for (int f = 0; f < 64; ++f) a += p[f] * Wf1[f * 32 + lane];
    hh[lane] = fmaxf(a, 0.f);
  }
  __syncthreads();
  if (lane < 8) {
    float a = bf2[lane];
#pragma unroll
    for (int j = 0; j < 32; ++j) a += hh[j] * Wf2[j * 8 + lane];
    out[g * 8 + lane] = a;
  }
}

extern "C" void kernel_launch(void* const* d_in, const int* in_sizes, int n_in,
                              void* d_out, int out_size, void* d_ws, size_t ws_size,
                              hipStream_t stream) {
  const float* x     = (const float*)d_in[0];
  const int*   ei    = (const int*)d_in[1];  // int64 in source -> int32 on device (JAX x64 off)
  const int*   batch = (const int*)d_in[2];
  const float* W1  = (const float*)d_in[3];
  const float* b1  = (const float*)d_in[4];
  const float* W2  = (const float*)d_in[5];
  const float* b2  = (const float*)d_in[6];
  const float* Wf1 = (const float*)d_in[7];
  const float* bf1 = (const float*)d_in[8];
  const float* Wf2 = (const float*)d_in[9];
  const float* bf2 = (const float*)d_in[10];
  float* out = (float*)d_out;

  const int N = in_sizes[0] / 128;  // 100000
  const int E = in_sizes[1] / 2;    // 3200000
  const int* src = ei;
  const int* dst = ei + E;
  const int nb = (N + 1023) / 1024;  // scan blocks (98)

  // workspace layout (d_ws widely aligned; all segments keep 16B alignment)
  int*      edata = (int*)d_ws;                        // E int              12.8 MB
  unsigned* xwA   = (unsigned*)(edata + E);            // N*32 uint (bf16x2) 12.8 MB
  unsigned* hB    = xwA + (size_t)N * 32;              // N*32 uint (bf16x2) 12.8 MB
  float*    dis   = (float*)(hB + (size_t)N * 32);     // N f
  int*      deg   = (int*)(dis + N);                   // N int
  int*      offs  = deg + N;                           // N+1 int
  int*      cur   = offs + N + 1;                      // N int
  int*      bsum  = cur + N;                           // 128 int
  float*    psum  = (float*)(bsum + 128);              // NGRAPHS*64 f
  float*    pcnt  = psum + NGRAPHS * 64;               // NGRAPHS f

  // ---- CSR build ----
  hipMemsetAsync(deg, 0, (size_t)N * sizeof(int), stream);
  hipMemsetAsync(cur, 0, (size_t)N * sizeof(int), stream);
  hist_kernel<<<2048, 256, 0, stream>>>(dst, deg, E);
  scan1_kernel<<<nb, 256, 0, stream>>>(deg, bsum, N);
  scan2_kernel<<<1, 64, 0, stream>>>(bsum, nb);
  scan3_kernel<<<nb, 256, 0, stream>>>(deg, bsum, offs, dis, N);
  fill_kernel<<<2048, 256, 0, stream>>>(src, dst, offs, cur, edata, E);

  // ---- conv1: xw' = bf16(dis * x@W1) ; gather(relu) -> hB (bf16) ----
  gemm1_kernel<<<(N + 15) / 16, 256, 0, stream>>>(x, W1, dis, (unsigned short*)xwA, N);
  gather_kernel<false><<<(N + 3) / 4, 256, 0, stream>>>(edata, offs, dis, (const uint4*)xwA,
                                                        b1, batch, (uint4*)hB, psum, pcnt, N);

  // ---- conv2: xw' = bf16(dis * h@W2) ; gather + pool ----
  gemm2_kernel<<<(N + 15) / 16, 256, 0, stream>>>(hB, W2, dis, (unsigned short*)xwA, N);
  hipMemsetAsync(psum, 0, (NGRAPHS * 64 + NGRAPHS) * sizeof(float), stream);
  gather_kernel<true><<<(N + 3) / 4, 256, 0, stream>>>(edata, offs, dis, (const uint4*)xwA,
                                                       b2, batch, (uint4*)hB, psum, pcnt, N);

  // ---- MLP head ----
  mlp_kernel<<<NGRAPHS, 64, 0, stream>>>(psum, pcnt, Wf1, bf1, Wf2, bf2, out);
}